// Round 4
// baseline (745.828 us; speedup 1.0000x reference)
//
#include <hip/hip_runtime.h>
#include <math.h>

#define NS_  4
#define NM_  8
#define NO_  4
#define H1_  4
#define H2_  9

#define EPT        4                 // edges per thread in edge_sorted
#define BLK_EDGES  (256 * EPT)       // 1024 edges per block
#define LOCAL_MAX  192               // LDS per-atom accumulator slots

struct __align__(16) Rec { float4 geo; int4 idx; };  // geo=(d,dx,dy,dz) idx=(i,jidx,jsym,0)

// ---------------------------------------------------------------------------
// count: histogram of iidx
// ---------------------------------------------------------------------------
__global__ __launch_bounds__(256) void count_kernel(
    const int* __restrict__ iidx, int* __restrict__ cnt, int nn)
{
    const int e = blockIdx.x * 256 + threadIdx.x;
    if (e < nn) atomicAdd(&cnt[iidx[e]], 1);
}

// exclusive scan of cnt[0..n) -> base[0..n] and cursor[0..n). single block.
__global__ __launch_bounds__(1024) void scan_kernel(
    const int* __restrict__ cnt, int* __restrict__ base,
    int* __restrict__ cursor, int n)
{
    __shared__ int wsum[16];
    __shared__ int carry;
    const int tid = threadIdx.x, lane = tid & 63, wid = tid >> 6;
    if (tid == 0) carry = 0;
    __syncthreads();
    for (int start = 0; start < n; start += 1024) {
        const int idx = start + tid;
        int v = (idx < n) ? cnt[idx] : 0;
        int s = v;
        #pragma unroll
        for (int d = 1; d < 64; d <<= 1) {
            int u = __shfl_up(s, d, 64);
            if (lane >= d) s += u;
        }
        if (lane == 63) wsum[wid] = s;
        __syncthreads();
        if (tid == 0) {
            int acc = carry;
            #pragma unroll
            for (int k = 0; k < 16; ++k) { int x = wsum[k]; wsum[k] = acc; acc += x; }
            carry = acc;
        }
        __syncthreads();
        if (idx < n) {
            const int b = (s - v) + wsum[wid];
            base[idx] = b;
            cursor[idx] = b;
        }
        __syncthreads();
    }
    if (tid == 0) base[n] = carry;
}

// scatter edge records into atom-sorted order
__global__ __launch_bounds__(256) void reorder_kernel(
    const int* __restrict__ iidx, const int* __restrict__ jidx,
    const int* __restrict__ jsym, const float* __restrict__ disp,
    const float* __restrict__ dist, int* __restrict__ cursor,
    Rec* __restrict__ rec, int nn)
{
    const int e = blockIdx.x * 256 + threadIdx.x;
    if (e >= nn) return;
    const int i = iidx[e];
    const int p = atomicAdd(&cursor[i], 1);
    Rec r;
    r.geo = make_float4(dist[e], disp[3 * e + 0], disp[3 * e + 1], disp[3 * e + 2]);
    r.idx = make_int4(i, jidx[e], jsym[e], 0);
    rec[p] = r;
}

// ---------------------------------------------------------------------------
// edge pass over sorted records: fused featurize + segment-sum into t[nta,16]
// ---------------------------------------------------------------------------
template <bool PASS1>
__global__ __launch_bounds__(256) void edge_sorted(
    const Rec* __restrict__ rec,
    const float* __restrict__ alpha, const float* __restrict__ rs,
    const float* __restrict__ csn_or_sp,   // PASS1: [NS,8]; else [NTA,8]
    const float* __restrict__ orbital,     // [2][8][4]
    const int* __restrict__ base,
    float* __restrict__ t, int nn)
{
    __shared__ float s_alpha[NS_ * NM_];
    __shared__ float s_rs[NS_ * NM_];
    __shared__ float s_sp[NS_ * NM_];
    __shared__ float s_W[2 * NM_ * NO_];
    __shared__ float acc[LOCAL_MAX * 16];
    __shared__ int s_lmin, s_lmax;

    const int tid = threadIdx.x;
    if (tid < NS_ * NM_) {
        s_alpha[tid] = alpha[tid];
        s_rs[tid]    = rs[tid];
        if (PASS1) s_sp[tid] = csn_or_sp[tid];
    }
    if (tid < 2 * NM_ * NO_) s_W[tid] = orbital[tid];
    for (int k = tid; k < LOCAL_MAX * 16; k += 256) acc[k] = 0.f;

    const int e0 = blockIdx.x * BLK_EDGES;
    const int e1 = min(e0 + BLK_EDGES, nn);
    if (tid == 0) { s_lmin = rec[e0].idx.x; s_lmax = rec[e1 - 1].idx.x; }
    __syncthreads();
    const int lmin = s_lmin, lmax = s_lmax;

    int cur = -1;
    float a[16];
    #pragma unroll
    for (int o = 0; o < 16; ++o) a[o] = 0.f;

    const int ebase = e0 + tid * EPT;
    #pragma unroll
    for (int k = 0; k < EPT; ++k) {
        const int e = ebase + k;
        if (e < e1) {
            const Rec r = rec[e];
            const int js = r.idx.z;
            const float d = r.geo.x;
            float c = __cosf(d * 0.52359877559829887308f);
            const float fc = 0.25f * (c + 1.0f) * (c + 1.0f);

            float cf[NM_];
            if (PASS1) {
                #pragma unroll
                for (int n = 0; n < NM_; ++n) {
                    const float dd = d - s_rs[js * NM_ + n];
                    cf[n] = fc * __expf(s_alpha[js * NM_ + n] * dd * dd) * s_sp[js * NM_ + n];
                }
            } else {
                const float4* c4 = (const float4*)(csn_or_sp + (size_t)r.idx.y * NM_);
                const float4 ca = c4[0], cb = c4[1];
                const float cj[NM_] = {ca.x, ca.y, ca.z, ca.w, cb.x, cb.y, cb.z, cb.w};
                #pragma unroll
                for (int n = 0; n < NM_; ++n) {
                    const float dd = d - s_rs[js * NM_ + n];
                    cf[n] = fc * __expf(s_alpha[js * NM_ + n] * dd * dd) * cj[n];
                }
            }

            float g0[NO_] = {0.f, 0.f, 0.f, 0.f};
            float g1[NO_] = {0.f, 0.f, 0.f, 0.f};
            #pragma unroll
            for (int n = 0; n < NM_; ++n) {
                const float v = cf[n];
                #pragma unroll
                for (int o = 0; o < NO_; ++o) {
                    g0[o] += v * s_W[(0 * NM_ + n) * NO_ + o];
                    g1[o] += v * s_W[(1 * NM_ + n) * NO_ + o];
                }
            }

            if (r.idx.x != cur) {
                // flush previous run
                if (cur >= 0) {
                    const int loc = cur - lmin;
                    if (loc < LOCAL_MAX) {
                        #pragma unroll
                        for (int o = 0; o < 16; ++o) atomicAdd(&acc[loc * 16 + o], a[o]);
                    } else {
                        #pragma unroll
                        for (int o = 0; o < 16; ++o) atomicAdd(&t[(size_t)cur * 16 + o], a[o]);
                    }
                }
                cur = r.idx.x;
                #pragma unroll
                for (int o = 0; o < 16; ++o) a[o] = 0.f;
            }
            #pragma unroll
            for (int o = 0; o < NO_; ++o) {
                a[o]      += g0[o];
                a[4 + o]  += r.geo.y * g1[o];
                a[8 + o]  += r.geo.z * g1[o];
                a[12 + o] += r.geo.w * g1[o];
            }
        }
    }
    if (cur >= 0) {
        const int loc = cur - lmin;
        if (loc < LOCAL_MAX) {
            #pragma unroll
            for (int o = 0; o < 16; ++o) atomicAdd(&acc[loc * 16 + o], a[o]);
        } else {
            #pragma unroll
            for (int o = 0; o < 16; ++o) atomicAdd(&t[(size_t)cur * 16 + o], a[o]);
        }
    }
    __syncthreads();

    // block flush: interior atoms -> plain store; boundary atoms -> atomic
    const int span = min(lmax - lmin + 1, LOCAL_MAX);
    for (int q = tid; q < span * 16; q += 256) {
        const int loc = q >> 4, o = q & 15;
        const int atom = lmin + loc;
        const float v = acc[loc * 16 + o];
        const bool interior = (base[atom] >= e0) && (base[atom + 1] <= e1);
        if (interior) t[(size_t)atom * 16 + o] = v;
        else          atomicAdd(&t[(size_t)atom * 16 + o], v);
    }
}

// ---------------------------------------------------------------------------
// FALLBACK PATH: direct f32 atomics (round-2 version, known-correct)
// ---------------------------------------------------------------------------
template <bool PASS1>
__global__ __launch_bounds__(256) void edge_atomic(
    const int* __restrict__ iidx, const int* __restrict__ jidx,
    const int* __restrict__ jsym, const float* __restrict__ disp,
    const float* __restrict__ dist,
    const float* __restrict__ alpha, const float* __restrict__ rs,
    const float* __restrict__ csn_or_sp, const float* __restrict__ orbital,
    float* __restrict__ t, int nn)
{
    __shared__ float s_alpha[NS_ * NM_];
    __shared__ float s_rs[NS_ * NM_];
    __shared__ float s_sp[NS_ * NM_];
    __shared__ float s_W[2 * NM_ * NO_];

    const int tid = threadIdx.x;
    if (tid < NS_ * NM_) {
        s_alpha[tid] = alpha[tid];
        s_rs[tid]    = rs[tid];
        if (PASS1) s_sp[tid] = csn_or_sp[tid];
    }
    if (tid < 2 * NM_ * NO_) s_W[tid] = orbital[tid];
    __syncthreads();

    const int e = blockIdx.x * 256 + tid;
    if (e >= nn) return;

    const int js = jsym[e];
    const float d = dist[e];
    float c = __cosf(d * 0.52359877559829887308f);
    const float fc = 0.25f * (c + 1.0f) * (c + 1.0f);
    const float dx = disp[3 * e + 0];
    const float dy = disp[3 * e + 1];
    const float dz = disp[3 * e + 2];

    float cf[NM_];
    if (PASS1) {
        #pragma unroll
        for (int n = 0; n < NM_; ++n) {
            const float dd = d - s_rs[js * NM_ + n];
            cf[n] = fc * __expf(s_alpha[js * NM_ + n] * dd * dd) * s_sp[js * NM_ + n];
        }
    } else {
        const int j = jidx[e];
        const float4* c4 = (const float4*)(csn_or_sp + (size_t)j * NM_);
        const float4 ca = c4[0], cb = c4[1];
        const float cj[NM_] = {ca.x, ca.y, ca.z, ca.w, cb.x, cb.y, cb.z, cb.w};
        #pragma unroll
        for (int n = 0; n < NM_; ++n) {
            const float dd = d - s_rs[js * NM_ + n];
            cf[n] = fc * __expf(s_alpha[js * NM_ + n] * dd * dd) * cj[n];
        }
    }

    float g0[NO_] = {0.f, 0.f, 0.f, 0.f};
    float g1[NO_] = {0.f, 0.f, 0.f, 0.f};
    #pragma unroll
    for (int n = 0; n < NM_; ++n) {
        const float v = cf[n];
        #pragma unroll
        for (int o = 0; o < NO_; ++o) {
            g0[o] += v * s_W[(0 * NM_ + n) * NO_ + o];
            g1[o] += v * s_W[(1 * NM_ + n) * NO_ + o];
        }
    }

    float* tb = t + (size_t)iidx[e] * 16;
    #pragma unroll
    for (int o = 0; o < NO_; ++o) atomicAdd(tb + o,      g0[o]);
    #pragma unroll
    for (int o = 0; o < NO_; ++o) atomicAdd(tb + 4 + o,  dx * g1[o]);
    #pragma unroll
    for (int o = 0; o < NO_; ++o) atomicAdd(tb + 8 + o,  dy * g1[o]);
    #pragma unroll
    for (int o = 0; o < NO_; ++o) atomicAdd(tb + 12 + o, dz * g1[o]);
}

// ---------------------------------------------------------------------------
// Per-atom kernels
// ---------------------------------------------------------------------------
__device__ __forceinline__ float silu_(float x) {
    return x / (1.0f + __expf(-x));
}

__global__ __launch_bounds__(256) void atom_mid_kernel(
    const int* __restrict__ symbols, const float* __restrict__ t,
    const float* __restrict__ sp,
    const float* __restrict__ w1, const float* __restrict__ b1,
    const float* __restrict__ w2, const float* __restrict__ b2,
    const float* __restrict__ w3, const float* __restrict__ b3,
    float* __restrict__ csn2, int nta)
{
    const int i = blockIdx.x * 256 + threadIdx.x;
    if (i >= nta) return;
    const int s = symbols[i];

    const float4* t4 = (const float4*)(t + (size_t)i * 16);
    const float4 q0 = t4[0], q1 = t4[1], q2 = t4[2], q3 = t4[3];
    float rho[NO_];
    rho[0] = q0.x * q0.x + q1.x * q1.x + q2.x * q2.x + q3.x * q3.x;
    rho[1] = q0.y * q0.y + q1.y * q1.y + q2.y * q2.y + q3.y * q3.y;
    rho[2] = q0.z * q0.z + q1.z * q1.z + q2.z * q2.z + q3.z * q3.z;
    rho[3] = q0.w * q0.w + q1.w * q1.w + q2.w * q2.w + q3.w * q3.w;

    float h1v[H1_];
    #pragma unroll
    for (int h = 0; h < H1_; ++h) {
        float a = b1[s * H1_ + h];
        #pragma unroll
        for (int o = 0; o < NO_; ++o) a += rho[o] * w1[(s * NO_ + o) * H1_ + h];
        h1v[h] = silu_(a);
    }
    float h2v[H2_];
    #pragma unroll
    for (int g = 0; g < H2_; ++g) {
        float a = b2[s * H2_ + g];
        #pragma unroll
        for (int h = 0; h < H1_; ++h) a += h1v[h] * w2[(s * H1_ + h) * H2_ + g];
        h2v[g] = silu_(a);
    }
    #pragma unroll
    for (int m = 0; m < NM_; ++m) {
        float a = b3[s * NM_ + m];
        #pragma unroll
        for (int g = 0; g < H2_; ++g) a += h2v[g] * w3[(s * H2_ + g) * NM_ + m];
        csn2[(size_t)i * NM_ + m] = sp[s * NM_ + m] + a;
    }
}

__global__ __launch_bounds__(256) void atom_out_kernel(
    const float* __restrict__ t, float* __restrict__ out, int nta)
{
    const int i = blockIdx.x * 256 + threadIdx.x;
    if (i >= nta) return;
    const float4* t4 = (const float4*)(t + (size_t)i * 16);
    const float4 q0 = t4[0], q1 = t4[1], q2 = t4[2], q3 = t4[3];
    float4 r;
    r.x = q0.x * q0.x + q1.x * q1.x + q2.x * q2.x + q3.x * q3.x;
    r.y = q0.y * q0.y + q1.y * q1.y + q2.y * q2.y + q3.y * q3.y;
    r.z = q0.z * q0.z + q1.z * q1.z + q2.z * q2.z + q3.z * q3.z;
    r.w = q0.w * q0.w + q1.w * q1.w + q2.w * q2.w + q3.w * q3.w;
    ((float4*)out)[i] = r;
}

// ---------------------------------------------------------------------------
extern "C" void kernel_launch(void* const* d_in, const int* in_sizes, int n_in,
                              void* d_out, int out_size, void* d_ws, size_t ws_size,
                              hipStream_t stream)
{
    const int*   symbols = (const int*)d_in[0];
    const int*   iidx    = (const int*)d_in[1];
    const int*   jidx    = (const int*)d_in[2];
    const int*   jsym    = (const int*)d_in[3];
    const float* disp    = (const float*)d_in[4];
    const float* dist    = (const float*)d_in[5];
    const float* alpha   = (const float*)d_in[6];
    const float* rs      = (const float*)d_in[7];
    const float* sp      = (const float*)d_in[8];
    const float* orb     = (const float*)d_in[9];
    const float* w1      = (const float*)d_in[10];
    const float* b1      = (const float*)d_in[11];
    const float* w2      = (const float*)d_in[12];
    const float* b2      = (const float*)d_in[13];
    const float* w3      = (const float*)d_in[14];
    const float* b3      = (const float*)d_in[15];

    const int nta = in_sizes[0];
    const int nn  = in_sizes[1];

    const int eb = (nn + 255) / 256;
    const int ab = (nta + 255) / 256;
    const int sb = (nn + BLK_EDGES - 1) / BLK_EDGES;

    char* ws = (char*)d_ws;
    auto al = [](size_t x) { return (x + 63) & ~(size_t)63; };

    size_t off = 0;
    size_t o_cnt  = off; off = al(off + (size_t)nta * 4);
    size_t o_base = off; off = al(off + ((size_t)nta + 1) * 4);
    size_t o_cur  = off; off = al(off + (size_t)nta * 4);
    size_t o_rec  = off; off = al(off + (size_t)nn * sizeof(Rec));
    size_t o_t    = off; off = al(off + (size_t)nta * 64);
    size_t o_c    = off; off = al(off + (size_t)nta * 32);
    const size_t need = off;

    if (ws_size >= need) {
        int*   cnt    = (int*)(ws + o_cnt);
        int*   base   = (int*)(ws + o_base);
        int*   cursor = (int*)(ws + o_cur);
        Rec*   rec    = (Rec*)(ws + o_rec);
        float* t      = (float*)(ws + o_t);
        float* csn2   = (float*)(ws + o_c);

        hipMemsetAsync(cnt, 0, (size_t)nta * 4, stream);
        count_kernel<<<eb, 256, 0, stream>>>(iidx, cnt, nn);
        scan_kernel<<<1, 1024, 0, stream>>>(cnt, base, cursor, nta);
        reorder_kernel<<<eb, 256, 0, stream>>>(iidx, jidx, jsym, disp, dist,
                                               cursor, rec, nn);
        hipMemsetAsync(t, 0, (size_t)nta * 64, stream);
        edge_sorted<true><<<sb, 256, 0, stream>>>(rec, alpha, rs, sp, orb,
                                                  base, t, nn);
        atom_mid_kernel<<<ab, 256, 0, stream>>>(symbols, t, sp, w1, b1, w2, b2,
                                                w3, b3, csn2, nta);
        hipMemsetAsync(t, 0, (size_t)nta * 64, stream);
        edge_sorted<false><<<sb, 256, 0, stream>>>(rec, alpha, rs, csn2,
                                                   orb + 2 * NM_ * NO_,
                                                   base, t, nn);
        atom_out_kernel<<<ab, 256, 0, stream>>>(t, (float*)d_out, nta);
    } else {
        // fallback: atomic path (round-2, known-correct)
        float* t    = (float*)d_ws;
        float* csn2 = t + (size_t)nta * 16;

        hipMemsetAsync(t, 0, (size_t)nta * 64, stream);
        edge_atomic<true><<<eb, 256, 0, stream>>>(iidx, jidx, jsym, disp, dist,
                                                  alpha, rs, sp, orb, t, nn);
        atom_mid_kernel<<<ab, 256, 0, stream>>>(symbols, t, sp, w1, b1, w2, b2,
                                                w3, b3, csn2, nta);
        hipMemsetAsync(t, 0, (size_t)nta * 64, stream);
        edge_atomic<false><<<eb, 256, 0, stream>>>(iidx, jidx, jsym, disp, dist,
                                                   alpha, rs, csn2, orb + 2 * NM_ * NO_,
                                                   t, nn);
        atom_out_kernel<<<ab, 256, 0, stream>>>(t, (float*)d_out, nta);
    }
}

// Round 5
// 647.717 us; speedup vs baseline: 1.1515x; 1.1515x over previous
//
#include <hip/hip_runtime.h>
#include <math.h>

#define NS_ 4
#define NM_ 8
#define NO_ 4
#define H1_ 4
#define H2_ 9

#define BLK_THREADS 256
#define EPT         8
#define BLK_EDGES   (BLK_THREADS * EPT)   // 2048 sorted edges per block
#define LOCAL_MAX   192                   // LDS per-atom slots
#define ACC_STRIDE  17                    // pad to break bank conflicts

// Record: q0=R[0..3], q1=R[4..7], q2=(dx,dy,dz,bitcast i), q3=(bitcast j, bitcast js, 0,0)
// R[n] = fcut(d) * exp(alpha[js,n]*(d-rs[js,n])^2)   (pass-invariant, computed once)

// ---------------------------------------------------------------------------
// rank: per-edge slot within its atom (returning atomics) — also builds cnt
// ---------------------------------------------------------------------------
__global__ __launch_bounds__(256) void rank_kernel(
    const int* __restrict__ iidx, int* __restrict__ cnt,
    int* __restrict__ rank, int nn)
{
    const int e = blockIdx.x * 256 + threadIdx.x;
    if (e < nn) rank[e] = atomicAdd(&cnt[iidx[e]], 1);
}

// exclusive scan of cnt[0..n) -> base[0..n]; single block, 16 elems/thread
__global__ __launch_bounds__(1024) void scan16_kernel(
    const int* __restrict__ cnt, int* __restrict__ base, int n)
{
    __shared__ int wsum[16];
    __shared__ int carry;
    const int tid = threadIdx.x, lane = tid & 63, wid = tid >> 6;
    if (tid == 0) carry = 0;
    __syncthreads();
    const int CH = 16 * 1024;      // elems per iteration
    for (int start = 0; start < n; start += CH) {
        const int i0 = start + tid * 16;
        int v[16];
        int s = 0;
        #pragma unroll
        for (int k = 0; k < 16; ++k) {
            v[k] = (i0 + k < n) ? cnt[i0 + k] : 0;
            s += v[k];
        }
        int t = s;
        #pragma unroll
        for (int d = 1; d < 64; d <<= 1) {
            int u = __shfl_up(t, d, 64);
            if (lane >= d) t += u;
        }
        if (lane == 63) wsum[wid] = t;
        __syncthreads();
        if (tid == 0) {
            int acc = carry;
            #pragma unroll
            for (int k = 0; k < 16; ++k) { int x = wsum[k]; wsum[k] = acc; acc += x; }
            carry = acc;
        }
        __syncthreads();
        int pre = (t - s) + wsum[wid];
        #pragma unroll
        for (int k = 0; k < 16; ++k) {
            if (i0 + k < n) base[i0 + k] = pre;
            pre += v[k];
        }
        __syncthreads();
    }
    if (tid == 0) base[n] = carry;
}

// ---------------------------------------------------------------------------
// featurize + scatter 64B records to sorted positions (write once, read twice)
// ---------------------------------------------------------------------------
__global__ __launch_bounds__(256) void feat_scatter(
    const int* __restrict__ iidx, const int* __restrict__ jidx,
    const int* __restrict__ jsym, const float* __restrict__ disp,
    const float* __restrict__ dist,
    const float* __restrict__ alpha, const float* __restrict__ rs,
    const int* __restrict__ base, const int* __restrict__ rank,
    float4* __restrict__ rec, int nn)
{
    __shared__ float s_alpha[NS_ * NM_];
    __shared__ float s_rs[NS_ * NM_];
    const int tid = threadIdx.x;
    if (tid < NS_ * NM_) { s_alpha[tid] = alpha[tid]; s_rs[tid] = rs[tid]; }
    __syncthreads();

    const int e = blockIdx.x * 256 + tid;
    if (e >= nn) return;

    const int i  = iidx[e];
    const int j  = jidx[e];
    const int js = jsym[e];
    const float d = dist[e];
    float c = __cosf(d * 0.52359877559829887308f);
    const float fc = 0.25f * (c + 1.0f) * (c + 1.0f);

    float R[NM_];
    #pragma unroll
    for (int n = 0; n < NM_; ++n) {
        const float dd = d - s_rs[js * NM_ + n];
        R[n] = fc * __expf(s_alpha[js * NM_ + n] * dd * dd);
    }

    const int p = base[i] + rank[e];
    float4* dst = rec + (size_t)p * 4;
    dst[0] = make_float4(R[0], R[1], R[2], R[3]);
    dst[1] = make_float4(R[4], R[5], R[6], R[7]);
    dst[2] = make_float4(disp[3 * e + 0], disp[3 * e + 1], disp[3 * e + 2],
                         __int_as_float(i));
    dst[3] = make_float4(__int_as_float(j), __int_as_float(js), 0.f, 0.f);
}

// ---------------------------------------------------------------------------
// density pass over sorted records: contract + wave-segmented reduce -> t
// ---------------------------------------------------------------------------
template <bool PASS1>
__global__ __launch_bounds__(256) void pass_reduce(
    const float4* __restrict__ rec,
    const float* __restrict__ sp_or_csn,   // PASS1: [NS,8]; else csn2 [NTA,8]
    const float* __restrict__ orbital,     // [2][8][4] = W0,W1
    const int* __restrict__ base,
    float* __restrict__ t, int nn)
{
    __shared__ float s_sp[NS_ * NM_];
    __shared__ float s_W[2 * NM_ * NO_];
    __shared__ float acc[LOCAL_MAX * ACC_STRIDE];
    __shared__ int s_lmin, s_lmax;

    const int tid = threadIdx.x;
    if (PASS1 && tid < NS_ * NM_) s_sp[tid] = sp_or_csn[tid];
    if (tid < 2 * NM_ * NO_) s_W[tid] = orbital[tid];
    for (int k = tid; k < LOCAL_MAX * ACC_STRIDE; k += BLK_THREADS) acc[k] = 0.f;

    const int e0 = blockIdx.x * BLK_EDGES;
    const int e1 = min(e0 + BLK_EDGES, nn);
    if (tid == 0) {
        s_lmin = __float_as_int(rec[(size_t)e0 * 4 + 2].w);
        s_lmax = __float_as_int(rec[(size_t)(e1 - 1) * 4 + 2].w);
    }
    __syncthreads();
    const int lmin = s_lmin;
    const int lane = tid & 63;

    #pragma unroll 1
    for (int k = 0; k < EPT; ++k) {
        const int e = e0 + k * BLK_THREADS + tid;
        int cur = -1;
        float a[16];
        #pragma unroll
        for (int o = 0; o < 16; ++o) a[o] = 0.f;

        if (e < e1) {
            const float4 q0 = rec[(size_t)e * 4 + 0];
            const float4 q1 = rec[(size_t)e * 4 + 1];
            const float4 q2 = rec[(size_t)e * 4 + 2];
            const float4 q3 = rec[(size_t)e * 4 + 3];
            cur = __float_as_int(q2.w);
            const float R[NM_] = {q0.x, q0.y, q0.z, q0.w, q1.x, q1.y, q1.z, q1.w};

            float cf[NM_];
            if (PASS1) {
                const int js = __float_as_int(q3.y);
                #pragma unroll
                for (int n = 0; n < NM_; ++n) cf[n] = R[n] * s_sp[js * NM_ + n];
            } else {
                const int j = __float_as_int(q3.x);
                const float4* c4 = (const float4*)(sp_or_csn + (size_t)j * NM_);
                const float4 ca = c4[0], cb = c4[1];
                const float cj[NM_] = {ca.x, ca.y, ca.z, ca.w, cb.x, cb.y, cb.z, cb.w};
                #pragma unroll
                for (int n = 0; n < NM_; ++n) cf[n] = R[n] * cj[n];
            }

            float g0[NO_] = {0.f, 0.f, 0.f, 0.f};
            float g1[NO_] = {0.f, 0.f, 0.f, 0.f};
            #pragma unroll
            for (int n = 0; n < NM_; ++n) {
                #pragma unroll
                for (int o = 0; o < NO_; ++o) {
                    g0[o] += cf[n] * s_W[n * NO_ + o];
                    g1[o] += cf[n] * s_W[NM_ * NO_ + n * NO_ + o];
                }
            }
            #pragma unroll
            for (int o = 0; o < NO_; ++o) {
                a[o]      = g0[o];
                a[4 + o]  = q2.x * g1[o];
                a[8 + o]  = q2.y * g1[o];
                a[12 + o] = q2.z * g1[o];
            }
        }

        // wave segmented suffix-sum keyed on cur (sorted-consecutive edges)
        #pragma unroll
        for (int d = 1; d < 64; d <<= 1) {
            const int ocur = __shfl_down(cur, d, 64);
            const bool take = (lane + d < 64) && (ocur == cur);
            #pragma unroll
            for (int o = 0; o < 16; ++o) {
                const float oa = __shfl_down(a[o], d, 64);
                if (take) a[o] += oa;
            }
        }
        const int pcur = __shfl_up(cur, 1, 64);
        const bool head = (cur >= 0) && (lane == 0 || pcur != cur);
        if (head) {
            const int loc = cur - lmin;
            if (loc >= 0 && loc < LOCAL_MAX) {
                #pragma unroll
                for (int o = 0; o < 16; ++o)
                    atomicAdd(&acc[loc * ACC_STRIDE + o], a[o]);
            } else {
                #pragma unroll
                for (int o = 0; o < 16; ++o)
                    atomicAdd(&t[(size_t)cur * 16 + o], a[o]);
            }
        }
    }
    __syncthreads();

    // block flush: interior atoms plain-store, boundary atoms atomic
    const int span = min(s_lmax - lmin + 1, LOCAL_MAX);
    for (int q = tid; q < span * 16; q += BLK_THREADS) {
        const int loc = q >> 4, o = q & 15;
        const int atom = lmin + loc;
        const float v = acc[loc * ACC_STRIDE + o];
        const bool interior = (base[atom] >= e0) && (base[atom + 1] <= e1);
        if (interior) t[(size_t)atom * 16 + o] = v;
        else          atomicAdd(&t[(size_t)atom * 16 + o], v);
    }
}

// ---------------------------------------------------------------------------
// FALLBACK: direct f32 atomics (round-2, known-correct)
// ---------------------------------------------------------------------------
template <bool PASS1>
__global__ __launch_bounds__(256) void edge_atomic(
    const int* __restrict__ iidx, const int* __restrict__ jidx,
    const int* __restrict__ jsym, const float* __restrict__ disp,
    const float* __restrict__ dist,
    const float* __restrict__ alpha, const float* __restrict__ rs,
    const float* __restrict__ csn_or_sp, const float* __restrict__ orbital,
    float* __restrict__ t, int nn)
{
    __shared__ float s_alpha[NS_ * NM_];
    __shared__ float s_rs[NS_ * NM_];
    __shared__ float s_sp[NS_ * NM_];
    __shared__ float s_W[2 * NM_ * NO_];

    const int tid = threadIdx.x;
    if (tid < NS_ * NM_) {
        s_alpha[tid] = alpha[tid];
        s_rs[tid]    = rs[tid];
        if (PASS1) s_sp[tid] = csn_or_sp[tid];
    }
    if (tid < 2 * NM_ * NO_) s_W[tid] = orbital[tid];
    __syncthreads();

    const int e = blockIdx.x * 256 + tid;
    if (e >= nn) return;

    const int js = jsym[e];
    const float d = dist[e];
    float c = __cosf(d * 0.52359877559829887308f);
    const float fc = 0.25f * (c + 1.0f) * (c + 1.0f);
    const float dx = disp[3 * e + 0];
    const float dy = disp[3 * e + 1];
    const float dz = disp[3 * e + 2];

    float cf[NM_];
    if (PASS1) {
        #pragma unroll
        for (int n = 0; n < NM_; ++n) {
            const float dd = d - s_rs[js * NM_ + n];
            cf[n] = fc * __expf(s_alpha[js * NM_ + n] * dd * dd) * s_sp[js * NM_ + n];
        }
    } else {
        const int j = jidx[e];
        const float4* c4 = (const float4*)(csn_or_sp + (size_t)j * NM_);
        const float4 ca = c4[0], cb = c4[1];
        const float cj[NM_] = {ca.x, ca.y, ca.z, ca.w, cb.x, cb.y, cb.z, cb.w};
        #pragma unroll
        for (int n = 0; n < NM_; ++n) {
            const float dd = d - s_rs[js * NM_ + n];
            cf[n] = fc * __expf(s_alpha[js * NM_ + n] * dd * dd) * cj[n];
        }
    }

    float g0[NO_] = {0.f, 0.f, 0.f, 0.f};
    float g1[NO_] = {0.f, 0.f, 0.f, 0.f};
    #pragma unroll
    for (int n = 0; n < NM_; ++n) {
        const float v = cf[n];
        #pragma unroll
        for (int o = 0; o < NO_; ++o) {
            g0[o] += v * s_W[n * NO_ + o];
            g1[o] += v * s_W[NM_ * NO_ + n * NO_ + o];
        }
    }

    float* tb = t + (size_t)iidx[e] * 16;
    #pragma unroll
    for (int o = 0; o < NO_; ++o) atomicAdd(tb + o,      g0[o]);
    #pragma unroll
    for (int o = 0; o < NO_; ++o) atomicAdd(tb + 4 + o,  dx * g1[o]);
    #pragma unroll
    for (int o = 0; o < NO_; ++o) atomicAdd(tb + 8 + o,  dy * g1[o]);
    #pragma unroll
    for (int o = 0; o < NO_; ++o) atomicAdd(tb + 12 + o, dz * g1[o]);
}

// ---------------------------------------------------------------------------
// per-atom kernels
// ---------------------------------------------------------------------------
__device__ __forceinline__ float silu_(float x) {
    return x / (1.0f + __expf(-x));
}

__global__ __launch_bounds__(256) void atom_mid_kernel(
    const int* __restrict__ symbols, const float* __restrict__ t,
    const float* __restrict__ sp,
    const float* __restrict__ w1, const float* __restrict__ b1,
    const float* __restrict__ w2, const float* __restrict__ b2,
    const float* __restrict__ w3, const float* __restrict__ b3,
    float* __restrict__ csn2, int nta)
{
    const int i = blockIdx.x * 256 + threadIdx.x;
    if (i >= nta) return;
    const int s = symbols[i];

    const float4* t4 = (const float4*)(t + (size_t)i * 16);
    const float4 q0 = t4[0], q1 = t4[1], q2 = t4[2], q3 = t4[3];
    float rho[NO_];
    rho[0] = q0.x * q0.x + q1.x * q1.x + q2.x * q2.x + q3.x * q3.x;
    rho[1] = q0.y * q0.y + q1.y * q1.y + q2.y * q2.y + q3.y * q3.y;
    rho[2] = q0.z * q0.z + q1.z * q1.z + q2.z * q2.z + q3.z * q3.z;
    rho[3] = q0.w * q0.w + q1.w * q1.w + q2.w * q2.w + q3.w * q3.w;

    float h1v[H1_];
    #pragma unroll
    for (int h = 0; h < H1_; ++h) {
        float a = b1[s * H1_ + h];
        #pragma unroll
        for (int o = 0; o < NO_; ++o) a += rho[o] * w1[(s * NO_ + o) * H1_ + h];
        h1v[h] = silu_(a);
    }
    float h2v[H2_];
    #pragma unroll
    for (int g = 0; g < H2_; ++g) {
        float a = b2[s * H2_ + g];
        #pragma unroll
        for (int h = 0; h < H1_; ++h) a += h1v[h] * w2[(s * H1_ + h) * H2_ + g];
        h2v[g] = silu_(a);
    }
    #pragma unroll
    for (int m = 0; m < NM_; ++m) {
        float a = b3[s * NM_ + m];
        #pragma unroll
        for (int g = 0; g < H2_; ++g) a += h2v[g] * w3[(s * H2_ + g) * NM_ + m];
        csn2[(size_t)i * NM_ + m] = sp[s * NM_ + m] + a;
    }
}

__global__ __launch_bounds__(256) void atom_out_kernel(
    const float* __restrict__ t, float* __restrict__ out, int nta)
{
    const int i = blockIdx.x * 256 + threadIdx.x;
    if (i >= nta) return;
    const float4* t4 = (const float4*)(t + (size_t)i * 16);
    const float4 q0 = t4[0], q1 = t4[1], q2 = t4[2], q3 = t4[3];
    float4 r;
    r.x = q0.x * q0.x + q1.x * q1.x + q2.x * q2.x + q3.x * q3.x;
    r.y = q0.y * q0.y + q1.y * q1.y + q2.y * q2.y + q3.y * q3.y;
    r.z = q0.z * q0.z + q1.z * q1.z + q2.z * q2.z + q3.z * q3.z;
    r.w = q0.w * q0.w + q1.w * q1.w + q2.w * q2.w + q3.w * q3.w;
    ((float4*)out)[i] = r;
}

// ---------------------------------------------------------------------------
extern "C" void kernel_launch(void* const* d_in, const int* in_sizes, int n_in,
                              void* d_out, int out_size, void* d_ws, size_t ws_size,
                              hipStream_t stream)
{
    const int*   symbols = (const int*)d_in[0];
    const int*   iidx    = (const int*)d_in[1];
    const int*   jidx    = (const int*)d_in[2];
    const int*   jsym    = (const int*)d_in[3];
    const float* disp    = (const float*)d_in[4];
    const float* dist    = (const float*)d_in[5];
    const float* alpha   = (const float*)d_in[6];
    const float* rs      = (const float*)d_in[7];
    const float* sp      = (const float*)d_in[8];
    const float* orb     = (const float*)d_in[9];
    const float* w1      = (const float*)d_in[10];
    const float* b1      = (const float*)d_in[11];
    const float* w2      = (const float*)d_in[12];
    const float* b2      = (const float*)d_in[13];
    const float* w3      = (const float*)d_in[14];
    const float* b3      = (const float*)d_in[15];

    const int nta = in_sizes[0];
    const int nn  = in_sizes[1];

    const int eb = (nn + 255) / 256;
    const int ab = (nta + 255) / 256;
    const int sb = (nn + BLK_EDGES - 1) / BLK_EDGES;

    char* ws = (char*)d_ws;
    auto al = [](size_t x) { return (x + 63) & ~(size_t)63; };

    size_t off = 0;
    size_t o_cnt  = off; off = al(off + (size_t)nta * 4);
    size_t o_base = off; off = al(off + ((size_t)nta + 1) * 4);
    size_t o_rank = off; off = al(off + (size_t)nn * 4);
    size_t o_rec  = off; off = al(off + (size_t)nn * 64);
    size_t o_t    = off; off = al(off + (size_t)nta * 64);
    size_t o_c    = off; off = al(off + (size_t)nta * 32);
    const size_t need = off;

    if (ws_size >= need) {
        int*    cnt  = (int*)(ws + o_cnt);
        int*    base = (int*)(ws + o_base);
        int*    rank = (int*)(ws + o_rank);
        float4* rec  = (float4*)(ws + o_rec);
        float*  t    = (float*)(ws + o_t);
        float*  csn2 = (float*)(ws + o_c);

        hipMemsetAsync(cnt, 0, (size_t)nta * 4, stream);
        rank_kernel<<<eb, 256, 0, stream>>>(iidx, cnt, rank, nn);
        scan16_kernel<<<1, 1024, 0, stream>>>(cnt, base, nta);
        feat_scatter<<<eb, 256, 0, stream>>>(iidx, jidx, jsym, disp, dist,
                                             alpha, rs, base, rank, rec, nn);
        hipMemsetAsync(t, 0, (size_t)nta * 64, stream);
        pass_reduce<true><<<sb, 256, 0, stream>>>(rec, sp, orb, base, t, nn);
        atom_mid_kernel<<<ab, 256, 0, stream>>>(symbols, t, sp, w1, b1, w2, b2,
                                                w3, b3, csn2, nta);
        hipMemsetAsync(t, 0, (size_t)nta * 64, stream);
        pass_reduce<false><<<sb, 256, 0, stream>>>(rec, csn2, orb + 2 * NM_ * NO_,
                                                   base, t, nn);
        atom_out_kernel<<<ab, 256, 0, stream>>>(t, (float*)d_out, nta);
    } else {
        // fallback: atomic path (round-2, known-correct)
        float* t    = (float*)d_ws;
        float* csn2 = t + (size_t)nta * 16;

        hipMemsetAsync(t, 0, (size_t)nta * 64, stream);
        edge_atomic<true><<<eb, 256, 0, stream>>>(iidx, jidx, jsym, disp, dist,
                                                  alpha, rs, sp, orb, t, nn);
        atom_mid_kernel<<<ab, 256, 0, stream>>>(symbols, t, sp, w1, b1, w2, b2,
                                                w3, b3, csn2, nta);
        hipMemsetAsync(t, 0, (size_t)nta * 64, stream);
        edge_atomic<false><<<eb, 256, 0, stream>>>(iidx, jidx, jsym, disp, dist,
                                                   alpha, rs, csn2, orb + 2 * NM_ * NO_,
                                                   t, nn);
        atom_out_kernel<<<ab, 256, 0, stream>>>(t, (float*)d_out, nta);
    }
}